// Round 2
// baseline (309.738 us; speedup 1.0000x reference)
//
#include <hip/hip_runtime.h>
#include <hip/hip_bf16.h>

typedef unsigned short u16;
typedef unsigned int u32;

#define NN 30
#define FF 4
#define EE 870        // N*(N-1)
#define BSZ 32        // B*S
#define CC 64         // T/TF
#define TT 128
#define NF 120        // NN*FF
#define TSTRIDE 15240 // 127*NN*FF
#define OUTHALF 487680 // BSZ*TSTRIDE (mu block size; var follows)

__device__ __forceinline__ float bf2f(u16 u) {
    union { u32 i; float f; } v; v.i = ((u32)u) << 16; return v.f;
}
__device__ __forceinline__ u16 f2bf(float f) {
    __hip_bfloat16 h = __float2bfloat16(f); return *(u16*)&h;
}
__device__ __forceinline__ float ldv(const void* p, int idx, int isbf) {
    float r;
    if (isbf) r = bf2f(((const u16*)p)[idx]);
    else      r = ((const float*)p)[idx];
    return r;
}
__device__ __forceinline__ void stv(void* p, int idx, float v, int isbf) {
    if (isbf) ((u16*)p)[idx] = f2bf(v);
    else      ((float*)p)[idx] = v;
}
__device__ __forceinline__ float softplus_clip(float z) {
    float sp = fmaxf(z, 0.f) + log1pf(expf(-fabsf(z)));
    return fminf(fmaxf(sp, 1e-8f), 100.f);
}

// Detect whether buffers are bf16 (flag=1) or fp32 (flag=0) by inspecting
// `graph`, whose entries are exactly 0.0f or 1.0f.
// bf16 layout: u16 words directly are entries -> even-indexed words hit 0x3F80 whp.
// fp32 layout: even-indexed u16 words are the low mantissa halves of 0.0/1.0 -> always 0x0000.
__global__ void dtype_probe(const u16* __restrict__ g, int* __restrict__ flag) {
    if (threadIdx.x == 0 && blockIdx.x == 0) {
        int bf = 0;
        for (int k = 0; k < 512; k += 2) {
            if (g[k] == 0x3F80u) bf = 1;
        }
        *flag = bf;
    }
}

__global__ __launch_bounds__(256, 2)
void sim_step(const void* __restrict__ data,     // step 0 input
              const float* __restrict__ prevF,   // step 1 input (fp32 ws) or null
              const void* __restrict__ prevOut,  // step 1 fallback: mu from out
              const void* __restrict__ graph,
              const void* __restrict__ mW1, const void* __restrict__ mB1,
              const void* __restrict__ mW2, const void* __restrict__ mB2,
              const void* __restrict__ aW1, const void* __restrict__ aB1,
              const void* __restrict__ aW2, const void* __restrict__ aB2,
              const void* __restrict__ aW3, const void* __restrict__ aB3,
              const void* __restrict__ vW1, const void* __restrict__ vB1,
              const void* __restrict__ vW2, const void* __restrict__ vB2,
              const void* __restrict__ vW3, const void* __restrict__ vB3,
              void* __restrict__ out,
              float* __restrict__ muNext,
              const int* __restrict__ dflag,
              int step)
{
    __shared__ float xN[NF];        // node features, fp32
    __shared__ float gR[EE];        // graph row
    __shared__ float pJ[NN * 64];   // sender partials
    __shared__ float bufS[NN * 64]; // s, then h1
    __shared__ float bufAgg[NN * 64];
    __shared__ float ngA[NN];

    const int tid  = threadIdx.x;
    const int lane = tid & 63;
    const int wv   = tid >> 6;       // 0..3
    const int bs   = blockIdx.x >> 6;
    const int c    = blockIdx.x & 63;
    const int isbf = dflag ? *dflag : 1;

    // ---- stage node features + graph row ----
    if (tid < NF) {
        float xv;
        if (step == 0)     xv = ldv(data, (bs * TT + 2 * c) * NF + tid, isbf);
        else if (prevF)    xv = prevF[(bs * CC + c) * NF + tid];
        else               xv = ldv(prevOut, bs * TSTRIDE + (2 * c) * NF + tid, isbf);
        xN[tid] = xv;
    }
    for (int n = tid; n < EE; n += 256) gR[n] = ldv(graph, bs * EE + n, isbf);

    // ---- per-lane small weights ----
    float w1r[8];
#pragma unroll
    for (int k = 0; k < 8; k++) w1r[k] = ldv(mW1, k * 64 + lane, isbf);
    const float b1r = ldv(mB1, lane, isbf);
    const float b2r = ldv(mB2, lane, isbf);
    const float ab1 = ldv(aB1, lane, isbf);
    const float ab2 = ldv(aB2, lane, isbf);
    const float vb1 = ldv(vB1, lane, isbf);
    const float vb2 = ldv(vB2, lane, isbf);
    float aw3[4], vw3[4], ab3[4], vb3r[4];
#pragma unroll
    for (int f = 0; f < 4; f++) {
        aw3[f]  = ldv(aW3, lane * 4 + f, isbf);
        vw3[f]  = ldv(vW3, lane * 4 + f, isbf);
        ab3[f]  = ldv(aB3, f, isbf);
        vb3r[f] = ldv(vB3, f, isbf);
    }
    __syncthreads();

    // ---- phase 1: sender partials pJ[j][h] ----
    for (int i = wv; i < NN; i += 4) {
        float a = xN[i*4]*w1r[4] + xN[i*4+1]*w1r[5] + xN[i*4+2]*w1r[6] + xN[i*4+3]*w1r[7];
        pJ[i * 64 + lane] = a;
    }
    __syncthreads();

    // ---- phase 2: edge accumulation s[h] = sum_j g*relu(pI+pJ), ng = sum_j g ----
    for (int i = wv; i < NN; i += 4) {
        float pI = b1r + xN[i*4]*w1r[0] + xN[i*4+1]*w1r[1] + xN[i*4+2]*w1r[2] + xN[i*4+3]*w1r[3];
        float s = 0.f, ng = 0.f;
        const float* gb = gR + i * 29;
#pragma unroll
        for (int e = 0; e < 29; e++) {
            int j = (e < i) ? e : e + 1;
            float g = gb[e];
            s = fmaf(g, fmaxf(pI + pJ[j * 64 + lane], 0.f), s);
            ng += g;
        }
        bufS[i * 64 + lane] = s;
        if (lane == 0) ngA[i] = ng;
    }
    __syncthreads();

    // weight-column register file for matvecs: wreg[k] = W[k][lane]
    float wreg[64];

    // ---- phase 3: agg = s @ W2 + ng*b2 ----
    if (isbf) {
#pragma unroll
        for (int k = 0; k < 64; k++) wreg[k] = bf2f(((const u16*)mW2)[k * 64 + lane]);
    } else {
#pragma unroll
        for (int k = 0; k < 64; k++) wreg[k] = ((const float*)mW2)[k * 64 + lane];
    }
    for (int i = wv; i < NN; i += 4) {
        float acc = ngA[i] * b2r;
        const float* src = bufS + i * 64;
#pragma unroll
        for (int k = 0; k < 64; k++) acc = fmaf(src[k], wreg[k], acc);
        bufAgg[i * 64 + lane] = acc;
    }
    __syncthreads();

    // ---- phase 4: h1m = relu(agg @ aW1 + ab1) ----
    if (isbf) {
#pragma unroll
        for (int k = 0; k < 64; k++) wreg[k] = bf2f(((const u16*)aW1)[k * 64 + lane]);
    } else {
#pragma unroll
        for (int k = 0; k < 64; k++) wreg[k] = ((const float*)aW1)[k * 64 + lane];
    }
    for (int i = wv; i < NN; i += 4) {
        float acc = ab1;
        const float* src = bufAgg + i * 64;
#pragma unroll
        for (int k = 0; k < 64; k++) acc = fmaf(src[k], wreg[k], acc);
        bufS[i * 64 + lane] = fmaxf(acc, 0.f);
    }
    __syncthreads();

    const int t = 2 * c + step;

    // ---- phase 5: h2m = relu(h1m @ aW2 + ab2); mu = h2m @ aW3 + ab3; write ----
    if (isbf) {
#pragma unroll
        for (int k = 0; k < 64; k++) wreg[k] = bf2f(((const u16*)aW2)[k * 64 + lane]);
    } else {
#pragma unroll
        for (int k = 0; k < 64; k++) wreg[k] = ((const float*)aW2)[k * 64 + lane];
    }
    for (int i = wv; i < NN; i += 4) {
        float acc = ab2;
        const float* src = bufS + i * 64;
#pragma unroll
        for (int k = 0; k < 64; k++) acc = fmaf(src[k], wreg[k], acc);
        float h2 = fmaxf(acc, 0.f);
        float m0 = h2 * aw3[0], m1 = h2 * aw3[1], m2 = h2 * aw3[2], m3 = h2 * aw3[3];
#pragma unroll
        for (int off = 32; off >= 1; off >>= 1) {
            m0 += __shfl_xor(m0, off);
            m1 += __shfl_xor(m1, off);
            m2 += __shfl_xor(m2, off);
            m3 += __shfl_xor(m3, off);
        }
        if (lane < 4) {
            float mv = (lane == 0) ? m0 : (lane == 1) ? m1 : (lane == 2) ? m2 : m3;
            mv += ab3[lane];
            if (t < 127) stv(out, bs * TSTRIDE + t * NF + i * 4 + lane, mv, isbf);
            if (muNext) muNext[(bs * CC + c) * NF + i * 4 + lane] = mv;
        }
    }
    __syncthreads();

    // ---- phase 6: h1v = relu(agg @ vW1 + vb1) ----
    if (isbf) {
#pragma unroll
        for (int k = 0; k < 64; k++) wreg[k] = bf2f(((const u16*)vW1)[k * 64 + lane]);
    } else {
#pragma unroll
        for (int k = 0; k < 64; k++) wreg[k] = ((const float*)vW1)[k * 64 + lane];
    }
    for (int i = wv; i < NN; i += 4) {
        float acc = vb1;
        const float* src = bufAgg + i * 64;
#pragma unroll
        for (int k = 0; k < 64; k++) acc = fmaf(src[k], wreg[k], acc);
        bufS[i * 64 + lane] = fmaxf(acc, 0.f);
    }
    __syncthreads();

    // ---- phase 7: h2v; var = clip(softplus(h2v @ vW3 + vb3)); write ----
    if (isbf) {
#pragma unroll
        for (int k = 0; k < 64; k++) wreg[k] = bf2f(((const u16*)vW2)[k * 64 + lane]);
    } else {
#pragma unroll
        for (int k = 0; k < 64; k++) wreg[k] = ((const float*)vW2)[k * 64 + lane];
    }
    for (int i = wv; i < NN; i += 4) {
        float acc = vb2;
        const float* src = bufS + i * 64;
#pragma unroll
        for (int k = 0; k < 64; k++) acc = fmaf(src[k], wreg[k], acc);
        float h2 = fmaxf(acc, 0.f);
        float v0 = h2 * vw3[0], v1 = h2 * vw3[1], v2 = h2 * vw3[2], v3 = h2 * vw3[3];
#pragma unroll
        for (int off = 32; off >= 1; off >>= 1) {
            v0 += __shfl_xor(v0, off);
            v1 += __shfl_xor(v1, off);
            v2 += __shfl_xor(v2, off);
            v3 += __shfl_xor(v3, off);
        }
        if (lane < 4) {
            float vv = (lane == 0) ? v0 : (lane == 1) ? v1 : (lane == 2) ? v2 : v3;
            vv = softplus_clip(vv + vb3r[lane]);
            if (t < 127) stv(out, OUTHALF + bs * TSTRIDE + t * NF + i * 4 + lane, vv, isbf);
        }
    }
}

extern "C" void kernel_launch(void* const* d_in, const int* in_sizes, int n_in,
                              void* d_out, int out_size, void* d_ws, size_t ws_size,
                              hipStream_t stream) {
    (void)in_sizes; (void)n_in; (void)out_size;

    const void* data  = d_in[0];
    const void* graph = d_in[1];
    const void* mW1 = d_in[2];  const void* mB1 = d_in[3];
    const void* mW2 = d_in[4];  const void* mB2 = d_in[5];
    const void* aW1 = d_in[6];  const void* aB1 = d_in[7];
    const void* aW2 = d_in[8];  const void* aB2 = d_in[9];
    const void* aW3 = d_in[10]; const void* aB3 = d_in[11];
    const void* vW1 = d_in[12]; const void* vB1 = d_in[13];
    const void* vW2 = d_in[14]; const void* vB2 = d_in[15];
    const void* vW3 = d_in[16]; const void* vB3 = d_in[17];

    // workspace layout: [0..3] dtype flag, [256..] fp32 mu chain
    int* dflag = nullptr;
    float* muNext = nullptr;
    const size_t needMu = 256 + (size_t)BSZ * CC * NF * sizeof(float);
    if (ws_size >= 16) dflag = (int*)d_ws;
    if (ws_size >= needMu) muNext = (float*)((char*)d_ws + 256);

    if (dflag) dtype_probe<<<1, 64, 0, stream>>>((const u16*)graph, dflag);

    dim3 grid(BSZ * CC);
    dim3 block(256);

    sim_step<<<grid, block, 0, stream>>>(data, nullptr, nullptr, graph,
        mW1, mB1, mW2, mB2, aW1, aB1, aW2, aB2, aW3, aB3,
        vW1, vB1, vW2, vB2, vW3, vB3, d_out, muNext, dflag, 0);

    sim_step<<<grid, block, 0, stream>>>(nullptr, muNext, d_out, graph,
        mW1, mB1, mW2, mB2, aW1, aB1, aW2, aB2, aW3, aB3,
        vW1, vB1, vW2, vB2, vW3, vB3, d_out, nullptr, dflag, 1);
}

// Round 3
// 203.818 us; speedup vs baseline: 1.5197x; 1.5197x over previous
//
#include <hip/hip_runtime.h>
#include <hip/hip_bf16.h>

typedef unsigned short u16;
typedef unsigned int u32;
typedef __attribute__((ext_vector_type(8))) __bf16 bfrag;   // MFMA A/B fragment (4 VGPRs)
typedef __attribute__((ext_vector_type(4))) float f32x4;    // MFMA C/D fragment

#define NN 30
#define FF 4
#define EE 870
#define BSZ 32
#define CC 64
#define TT 128
#define NF 120
#define TSTRIDE 15240
#define OUTHALF 487680
#define AST 72            // activation LDS row stride in u16 (144 B: 16B-aligned, breaks conflicts)

// ws layout: [0..3] int dtype flag; at +256: u16 weights (B-fragment order, o-major):
//   +0     W2T(msg)  64x64
//   +4096  A1T(mean) 64x64
//   +8192  A2T(mean) 64x64
//   +12288 V1T(var)  64x64
//   +16384 V2T(var)  64x64
//   +20480 A3T 16x64 (rows 4..15 zero)
//   +21504 V3T 16x64
// at +256+45056: u32 gmask[BSZ*NN]
#define WS_WOFF 256
#define WS_MASKOFF (256 + 45056)

__device__ __forceinline__ float bf2f(u16 u) {
    union { u32 i; float f; } v; v.i = ((u32)u) << 16; return v.f;
}
__device__ __forceinline__ u16 f2bf(float f) {
    __hip_bfloat16 h = __float2bfloat16(f); return *(u16*)&h;
}
__device__ __forceinline__ float ldv(const void* p, int idx, int isbf) {
    if (isbf) return bf2f(((const u16*)p)[idx]);
    return ((const float*)p)[idx];
}
__device__ __forceinline__ float softplus_clip(float z) {
    float sp = fmaxf(z, 0.f) + log1pf(expf(-fabsf(z)));
    return fminf(fmaxf(sp, 1e-8f), 100.f);
}
__device__ __forceinline__ f32x4 MFMA(bfrag a, bfrag b, f32x4 c) {
    return __builtin_amdgcn_mfma_f32_16x16x32_bf16(a, b, c, 0, 0, 0);
}

// ---- dtype probe: graph entries are exactly 0.0/1.0. bf16 layout -> some even
// u16 word == 0x3F80; fp32 layout -> even words (low mantissa halves) all 0.
__global__ void dtype_probe(const u16* __restrict__ g, int* __restrict__ flag) {
    int hit = (g[threadIdx.x * 2] == 0x3F80u) ? 1 : 0;
    unsigned long long b = __ballot(hit);
    if (threadIdx.x == 0) *flag = (b != 0ull) ? 1 : 0;
}

// ---- prep: transpose weights to B-fragment-friendly o-major bf16; build edge masks
__global__ void prep_ws(const void* __restrict__ mW2,
                        const void* __restrict__ aW1, const void* __restrict__ aW2,
                        const void* __restrict__ vW1, const void* __restrict__ vW2,
                        const void* __restrict__ aW3, const void* __restrict__ vW3,
                        const void* __restrict__ graph,
                        const int* __restrict__ flag,
                        u16* __restrict__ wsW, u32* __restrict__ wsMask) {
    const int gtid = blockIdx.x * blockDim.x + threadIdx.x;
    const int gstr = gridDim.x * blockDim.x;
    const int isbf = *flag;
    for (int idx = gtid; idx < 4096; idx += gstr) {
        int k = idx >> 6, o = idx & 63;
        int d = o * 64 + k;
        wsW[d]         = f2bf(ldv(mW2, idx, isbf));
        wsW[4096 + d]  = f2bf(ldv(aW1, idx, isbf));
        wsW[8192 + d]  = f2bf(ldv(aW2, idx, isbf));
        wsW[12288 + d] = f2bf(ldv(vW1, idx, isbf));
        wsW[16384 + d] = f2bf(ldv(vW2, idx, isbf));
    }
    for (int idx = gtid; idx < 1024; idx += gstr) {
        int f = idx >> 6, h = idx & 63;
        wsW[20480 + idx] = (f < 4) ? f2bf(ldv(aW3, h * 4 + f, isbf)) : (u16)0;
        wsW[21504 + idx] = (f < 4) ? f2bf(ldv(vW3, h * 4 + f, isbf)) : (u16)0;
    }
    for (int idx = gtid; idx < BSZ * NN; idx += gstr) {
        int b = idx / NN, i = idx % NN;
        u32 m = 0;
        for (int e = 0; e < 29; e++)
            if (ldv(graph, b * EE + i * 29 + e, isbf) > 0.5f) m |= (1u << e);
        wsMask[idx] = m;
    }
}

__global__ __launch_bounds__(256, 4)
void sim_fused(const void* __restrict__ data,
               const void* __restrict__ mW1, const void* __restrict__ mB1,
               const void* __restrict__ mB2,
               const void* __restrict__ aB1, const void* __restrict__ aB2,
               const void* __restrict__ aB3,
               const void* __restrict__ vB1, const void* __restrict__ vB2,
               const void* __restrict__ vB3,
               const u16* __restrict__ wsW, const u32* __restrict__ wsMask,
               void* __restrict__ out,
               const int* __restrict__ dflag)
{
    __shared__ __align__(16) float xN[NF];
    __shared__ __align__(16) float pJ[NN * 64];
    __shared__ __align__(16) u32 gmask[NN];
    __shared__ __align__(16) float ngS[32];
    __shared__ __align__(16) u16 S[32 * AST];
    __shared__ __align__(16) u16 bufA[32 * AST];
    __shared__ __align__(16) u16 bufHm[32 * AST];
    __shared__ __align__(16) u16 bufHv[32 * AST];
    __shared__ __align__(16) u16 bufH2m[32 * AST];
    __shared__ __align__(16) u16 bufH2v[32 * AST];

    const int tid  = threadIdx.x;
    const int lane = tid & 63;
    const int wv   = tid >> 6;        // 0..3
    const int ln15 = lane & 15;
    const int quad = lane >> 4;
    const int bs   = blockIdx.x >> 6;
    const int c    = blockIdx.x & 63;
    const int isbf = *dflag;

    const bool isMean = (wv < 2);
    const int rb = wv & 1;            // row-block (16 rows) this wave owns

    // ---- setup ----
    if (tid < NF) xN[tid] = ldv(data, (bs * TT + 2 * c) * NF + tid, isbf);
    if (tid < NN) {
        u32 m = wsMask[bs * NN + tid];
        gmask[tid] = m;
        ngS[tid] = (float)__popc(m);
    }
    if (tid >= NN && tid < 32) ngS[tid] = 0.f;
    if (tid < 128) S[(30 + (tid >> 6)) * AST + (tid & 63)] = 0;  // zero pad rows

    float w1r[8];
#pragma unroll
    for (int k = 0; k < 8; k++) w1r[k] = ldv(mW1, k * 64 + lane, isbf);
    const float b1r = ldv(mB1, lane, isbf);

    float b2c[2];
    b2c[0] = ldv(mB2, (wv >> 1) * 32 + ln15, isbf);
    b2c[1] = ldv(mB2, (wv >> 1) * 32 + 16 + ln15, isbf);

    float h1b[4], h2b[4], b3r[4];
#pragma unroll
    for (int cb = 0; cb < 4; cb++) {
        h1b[cb] = ldv(isMean ? aB1 : vB1, cb * 16 + ln15, isbf);
        h2b[cb] = ldv(isMean ? aB2 : vB2, cb * 16 + ln15, isbf);
    }
#pragma unroll
    for (int r = 0; r < 4; r++) b3r[r] = ldv(isMean ? aB3 : vB3, r, isbf);

    const u16* W2T = wsW;
    const u16* H1T = isMean ? (wsW + 4096)  : (wsW + 12288);
    const u16* H2T = isMean ? (wsW + 8192)  : (wsW + 16384);
    const u16* W3T = isMean ? (wsW + 20480) : (wsW + 21504);
    u16* bufH  = isMean ? bufHm  : bufHv;
    u16* bufH2 = isMean ? bufH2m : bufH2v;

    __syncthreads();

    for (int step = 0; step < 2; step++) {
        // ---- pJ[j][h] = x_j . W1[4:8, h] ----
        for (int i = wv; i < NN; i += 4) {
            pJ[i * 64 + lane] = xN[i*4] * w1r[4] + xN[i*4+1] * w1r[5]
                              + xN[i*4+2] * w1r[6] + xN[i*4+3] * w1r[7];
        }
        __syncthreads();

        // ---- edge accumulation: S[i][h] = sum_{j active} relu(pI + pJ) ----
        for (int i = wv; i < NN; i += 4) {
            float pI = b1r + xN[i*4] * w1r[0] + xN[i*4+1] * w1r[1]
                           + xN[i*4+2] * w1r[2] + xN[i*4+3] * w1r[3];
            u32 gm = __builtin_amdgcn_readfirstlane(gmask[i]);
            float s = 0.f;
#pragma unroll
            for (int e = 0; e < 29; e++) {
                if (gm & (1u << e)) {
                    int j = e + (e >= i);
                    s += fmaxf(pI + pJ[j * 64 + lane], 0.f);
                }
            }
            S[i * AST + lane] = f2bf(s);
        }
        __syncthreads();

        // ---- agg = S @ W2 + ng*b2 (all 4 waves, 2 tiles each) ----
        {
            bfrag a0 = *(const bfrag*)&S[(rb * 16 + ln15) * AST + quad * 8];
            bfrag a1 = *(const bfrag*)&S[(rb * 16 + ln15) * AST + 32 + quad * 8];
#pragma unroll
            for (int t2 = 0; t2 < 2; t2++) {
                int cb = (wv >> 1) * 2 + t2;
                bfrag b0 = *(const bfrag*)&W2T[(cb * 16 + ln15) * 64 + quad * 8];
                bfrag b1 = *(const bfrag*)&W2T[(cb * 16 + ln15) * 64 + 32 + quad * 8];
                f32x4 acc = {0.f, 0.f, 0.f, 0.f};
                acc = MFMA(a0, b0, acc);
                acc = MFMA(a1, b1, acc);
#pragma unroll
                for (int r = 0; r < 4; r++) {
                    int row = rb * 16 + quad * 4 + r;
                    bufA[row * AST + cb * 16 + ln15] = f2bf(acc[r] + ngS[row] * b2c[t2]);
                }
            }
        }
        __syncthreads();

        // ---- h1 = relu(agg @ W1 + b1)  (waves 0,1 mean | 2,3 var; 4 tiles each) ----
        {
            bfrag a0 = *(const bfrag*)&bufA[(rb * 16 + ln15) * AST + quad * 8];
            bfrag a1 = *(const bfrag*)&bufA[(rb * 16 + ln15) * AST + 32 + quad * 8];
#pragma unroll
            for (int cb = 0; cb < 4; cb++) {
                bfrag b0 = *(const bfrag*)&H1T[(cb * 16 + ln15) * 64 + quad * 8];
                bfrag b1 = *(const bfrag*)&H1T[(cb * 16 + ln15) * 64 + 32 + quad * 8];
                f32x4 acc = {0.f, 0.f, 0.f, 0.f};
                acc = MFMA(a0, b0, acc);
                acc = MFMA(a1, b1, acc);
#pragma unroll
                for (int r = 0; r < 4; r++) {
                    int row = rb * 16 + quad * 4 + r;
                    bufH[row * AST + cb * 16 + ln15] = f2bf(fmaxf(acc[r] + h1b[cb], 0.f));
                }
            }
        }
        __syncthreads();

        // ---- h2 = relu(h1 @ W2' + b2') ----
        {
            bfrag a0 = *(const bfrag*)&bufH[(rb * 16 + ln15) * AST + quad * 8];
            bfrag a1 = *(const bfrag*)&bufH[(rb * 16 + ln15) * AST + 32 + quad * 8];
#pragma unroll
            for (int cb = 0; cb < 4; cb++) {
                bfrag b0 = *(const bfrag*)&H2T[(cb * 16 + ln15) * 64 + quad * 8];
                bfrag b1 = *(const bfrag*)&H2T[(cb * 16 + ln15) * 64 + 32 + quad * 8];
                f32x4 acc = {0.f, 0.f, 0.f, 0.f};
                acc = MFMA(a0, b0, acc);
                acc = MFMA(a1, b1, acc);
#pragma unroll
                for (int r = 0; r < 4; r++) {
                    int row = rb * 16 + quad * 4 + r;
                    bufH2[row * AST + cb * 16 + ln15] = f2bf(fmaxf(acc[r] + h2b[cb], 0.f));
                }
            }
        }
        __syncthreads();

        // ---- epilogue: out^T = W3T(16x64-padded) @ h2^T; quad 0 holds f=reg ----
        {
            const int nb = rb;  // wave's node-block
            bfrag a0 = *(const bfrag*)&W3T[ln15 * 64 + quad * 8];
            bfrag a1 = *(const bfrag*)&W3T[ln15 * 64 + 32 + quad * 8];
            bfrag b0 = *(const bfrag*)&bufH2[(nb * 16 + ln15) * AST + quad * 8];
            bfrag b1 = *(const bfrag*)&bufH2[(nb * 16 + ln15) * AST + 32 + quad * 8];
            f32x4 acc = {0.f, 0.f, 0.f, 0.f};
            acc = MFMA(a0, b0, acc);
            acc = MFMA(a1, b1, acc);
            const int n = nb * 16 + ln15;
            const int t = 2 * c + step;
            if (quad == 0 && n < NN) {
                float v[4];
#pragma unroll
                for (int r = 0; r < 4; r++) v[r] = acc[r] + b3r[r];
                if (!isMean) {
#pragma unroll
                    for (int r = 0; r < 4; r++) v[r] = softplus_clip(v[r]);
                }
                if (t < 127) {
                    size_t o = (size_t)bs * TSTRIDE + (size_t)t * NF + n * 4
                             + (isMean ? 0 : OUTHALF);
                    if (isbf) {
                        u16* op = (u16*)out;
                        u32 lo = (u32)f2bf(v[0]) | ((u32)f2bf(v[1]) << 16);
                        u32 hi = (u32)f2bf(v[2]) | ((u32)f2bf(v[3]) << 16);
                        *(u32*)&op[o] = lo;
                        *(u32*)&op[o + 2] = hi;
                    } else {
                        float* op = (float*)out;
                        op[o] = v[0]; op[o+1] = v[1]; op[o+2] = v[2]; op[o+3] = v[3];
                    }
                }
                if (isMean && step == 0) {
                    xN[n*4]   = v[0]; xN[n*4+1] = v[1];
                    xN[n*4+2] = v[2]; xN[n*4+3] = v[3];
                }
            }
        }
        __syncthreads();
    }
}

extern "C" void kernel_launch(void* const* d_in, const int* in_sizes, int n_in,
                              void* d_out, int out_size, void* d_ws, size_t ws_size,
                              hipStream_t stream) {
    (void)in_sizes; (void)n_in; (void)out_size; (void)ws_size;

    const void* data  = d_in[0];
    const void* graph = d_in[1];
    const void* mW1 = d_in[2];  const void* mB1 = d_in[3];
    const void* mW2 = d_in[4];  const void* mB2 = d_in[5];
    const void* aW1 = d_in[6];  const void* aB1 = d_in[7];
    const void* aW2 = d_in[8];  const void* aB2 = d_in[9];
    const void* aW3 = d_in[10]; const void* aB3 = d_in[11];
    const void* vW1 = d_in[12]; const void* vB1 = d_in[13];
    const void* vW2 = d_in[14]; const void* vB2 = d_in[15];
    const void* vW3 = d_in[16]; const void* vB3 = d_in[17];

    int* dflag   = (int*)d_ws;
    u16* wsW     = (u16*)((char*)d_ws + WS_WOFF);
    u32* wsMask  = (u32*)((char*)d_ws + WS_MASKOFF);

    dtype_probe<<<1, 64, 0, stream>>>((const u16*)graph, dflag);

    prep_ws<<<8, 256, 0, stream>>>(mW2, aW1, aW2, vW1, vW2, aW3, vW3,
                                   graph, dflag, wsW, wsMask);

    sim_fused<<<BSZ * CC, 256, 0, stream>>>(data,
        mW1, mB1, mB2, aB1, aB2, aB3, vB1, vB2, vB3,
        wsW, wsMask, d_out, dflag);
}